// Round 13
// baseline (194.926 us; speedup 1.0000x reference)
//
#include <hip/hip_runtime.h>
#include <hip/hip_bf16.h>

// Problem constants
#define BB 2
#define CC 256
#define HH 96
#define WW 96
#define HWP (HH*WW)        // 9216
#define NTOT (BB*HWP)      // 18432 flattened (b,p)
#define K1 2304            // 256*9, GEMM K for both convs
#define NKT 36             // K1/64 k-steps
#define KHS 18             // k-steps per split-K half (gemm2)

// d_out layout: logits[2,1,96,96], bbox[2,4,96,96], shape[2,2,96,96], loc[2,1,96,96]
#define OUT_LOGITS 0
#define OUT_BBOX   (2*1*HWP)
#define OUT_SHAPE  (OUT_BBOX + 2*4*HWP)
#define OUT_LOC    (OUT_SHAPE + 2*2*HWP)

typedef __attribute__((ext_vector_type(8))) short short8v;   // 8 bf16 (4 VGPRs)
typedef __attribute__((ext_vector_type(4))) float f32x4;

// XCD-aware swizzles: contiguous slab of consecutive n-blocks per XCD.
__device__ __forceinline__ int xcd_swizzle288(int bx) {   // 288 = 8 x 36
    return (bx & 7) * 36 + (bx >> 3);
}
__device__ __forceinline__ int xcd_swizzle576(int bx) {   // 576 = 8 x 72
    return (bx & 7) * 72 + (bx >> 3);
}

__device__ __forceinline__ float bf2f(unsigned short u) {
    return __uint_as_float(((unsigned)u) << 16);
}
__device__ __forceinline__ unsigned short f2bf(float f) {
    unsigned u = __float_as_uint(f);
    u += 0x7FFFu + ((u >> 16) & 1u);           // round-to-nearest-even
    return (unsigned short)(u >> 16);
}

// ------- prep: weights -> bf16 PRE-SWIZZLED A panels + zero page ------------
__global__ __launch_bounds__(256) void prep_kernel(
    const float* __restrict__ conv_w, const float* __restrict__ adapt_w,
    unsigned short* __restrict__ W1p, unsigned short* __restrict__ W2p,
    unsigned short* __restrict__ zp)
{
    const int t = blockIdx.x * 256 + threadIdx.x;
    if (t < 1024) zp[t] = 0;                    // zero page (ws is re-poisoned!)
    if (t < CC * K1) {
        const int e = t & 7;
        {   // W1p
            const int s  = (t >> 3) & 1023;
            const int r  = t >> 13;             // cb*36+kt, [0,72)
            const int kt = r % 36, cb = r / 36;
            const int row = s & 127, kc = s >> 7;
            const int co = cb * 128 + row;
            const int k  = kt * 64 + kc * 8 + e;
            const int kk = k >> 8, ci = k & 255;
            W1p[t] = f2bf(conv_w[co * K1 + ci * 9 + kk]);
        }
        {   // W2p
            const int s  = (t >> 3) & 2047;
            const int kt = t >> 14;             // [0,36)
            const int row = s & 255, kc = s >> 8;
            const int k  = kt * 64 + kc * 8 + e;
            const int kk = k >> 8, ci = k & 255;
            W2p[t] = f2bf(adapt_w[row * K1 + ci * 9 + kk]);
        }
    }
}

// ------------- transpose feature [b][c][p] fp32 -> f_cf [b][p][c] bf16 ------
// R12: store phase vectorized to ushort4 (512 B/wave-instr vs 128 B scalar).
__global__ __launch_bounds__(256) void transpose_kernel(
    const float* __restrict__ f, unsigned short* __restrict__ fcf)
{
    __shared__ unsigned short tile[64][66];     // +2 pad
    const int p0 = blockIdx.x * 64;
    const int cc = blockIdx.y;
    const int b  = blockIdx.z;
    const int tx = threadIdx.x & 63, ty = threadIdx.x >> 6;
#pragma unroll
    for (int ii = 0; ii < 16; ii++) {
        const int cl = ii * 4 + ty;
        tile[cl][tx] = f2bf(f[((size_t)b * CC + cc * 64 + cl) * HWP + p0 + tx]);
    }
    __syncthreads();
    const int tx4 = threadIdx.x & 15;           // c-quad index (c = tx4*4..+3)
    const int py  = threadIdx.x >> 4;           // pixel sub-index (0..15)
#pragma unroll
    for (int ii = 0; ii < 4; ii++) {
        const int pl = ii * 16 + py;
        ushort4 v;
        v.x = tile[tx4 * 4 + 0][pl];
        v.y = tile[tx4 * 4 + 1][pl];
        v.z = tile[tx4 * 4 + 2][pl];
        v.w = tile[tx4 * 4 + 3][pl];
        *(ushort4*)(fcf + ((size_t)(b * HWP + p0 + pl)) * CC + cc * 64 + tx4 * 4) = v;
    }
}

// --------- GEMM1: t = relu(W1 x im2col + bias), 512 thr / 8 waves -----------
// M=128 x N=64, BK=64. R13: cb folded into blockIdx.x (bx&1) — consecutive
// dispatched blocks are the (cb=0,cb=1) PAIR of the same n0: they read
// IDENTICAL B data (L2-shared on same XCD) and co-fill CUs in one pass
// (R12 y-dim dispatch ran cb=0 then cb=1 sequentially at half occupancy).
// K-loop R9-exact: A-direct from L2-resident W1p, depth-1 B prefetch.
__global__ __launch_bounds__(512, 6) void gemm1_kernel(
    const unsigned short* __restrict__ W1p, const unsigned short* __restrict__ fcf,
    const float* __restrict__ bias, const unsigned short* __restrict__ zp,
    unsigned short* __restrict__ tcf)
{
    __shared__ short Bs[2][4096];               // 2 x 8 KB (XOR-swizzled)
    const int tid  = threadIdx.x;
    const int lane = tid & 63, w = tid >> 6;    // w in [0,8)
    const int quad = lane >> 4, r15 = lane & 15;
    const int cb  = blockIdx.x & 1;             // interleaved co-half
    const int n0  = xcd_swizzle288(blockIdx.x >> 1) * 64;
    const int co0 = cb * 128;
    const int wm = w & 3, wn = w >> 2;          // co-quarter (32 rows), n-half

    // B staging geometry: thread -> (pixel pr, 8-ch chunk kc)
    const int pr = tid >> 3, kc = tid & 7;
    const int xsw = (pr * 8 + (kc ^ (pr & 7))) * 8;   // Bs write slot (shorts)
    const int nb = n0 + pr;
    const int b  = nb / HWP;
    const int p  = nb - b * HWP;
    const int y = p / WW, x = p % WW;
    const unsigned short* fb = fcf + (size_t)b * HWP * CC;

    f32x4 acc[2][2];
#pragma unroll
    for (int i = 0; i < 2; i++)
#pragma unroll
        for (int j = 0; j < 2; j++) acc[i][j] = (f32x4){0.f, 0.f, 0.f, 0.f};

    auto loadB = [&](int kt) -> short8v {
        const int kk  = kt >> 2;
        const int ci0 = (kt & 3) * 64;
        const int yy = y + kk / 3 - 1, xx = x + kk % 3 - 1;
        const bool ok = (yy >= 0) && (yy < HH) && (xx >= 0) && (xx < WW);
        const unsigned short* src = ok
            ? fb + (size_t)(yy * WW + xx) * CC + ci0 + kc * 8
            : zp;
        return *(const short8v*)src;
    };
    // A-fragment direct from global: slot = kchunk*128 + row within kt-panel.
    auto mma = [&](int buf, int kt) {
        const unsigned short* pnl = W1p + ((size_t)(cb * 36 + kt) * 1024) * 8;
#pragma unroll
        for (int ks = 0; ks < 2; ks++) {
            short8v a[2], bf[2];
            const int kchunk = ks * 4 + quad;
#pragma unroll
            for (int i = 0; i < 2; i++)
                a[i] = *(const short8v*)(pnl + (size_t)(kchunk * 128 + wm * 32 + i * 16 + r15) * 8);
#pragma unroll
            for (int j = 0; j < 2; j++) {
                const int row = wn * 32 + j * 16 + r15;
                bf[j] = *(const short8v*)&Bs[buf][(row * 8 + (kchunk ^ (row & 7))) * 8];
            }
#pragma unroll
            for (int i = 0; i < 2; i++)
#pragma unroll
                for (int j = 0; j < 2; j++)
                    acc[i][j] = __builtin_amdgcn_mfma_f32_16x16x32_bf16(a[i], bf[j], acc[i][j], 0, 0, 0);
        }
    };

    { short8v b0 = loadB(0); *(short8v*)&Bs[0][xsw] = b0; }
    __syncthreads();
    int cur = 0;
    for (int kt = 0; kt < NKT - 1; kt++) {
        const int nxt = cur ^ 1;
        short8v bn = loadB(kt + 1);             // -> regs, latency under MFMA
        mma(cur, kt);
        *(short8v*)&Bs[nxt][xsw] = bn;
        __syncthreads();
        cur = nxt;
    }
    mma(cur, NKT - 1);                          // peeled last tile

    // epilogue: bias + relu -> t_cf[n][c] bf16 (C/D map: col=lane&15, row=quad*4+reg)
#pragma unroll
    for (int i = 0; i < 2; i++) {
        const int m = co0 + wm * 32 + i * 16 + quad * 4;
        const float b0 = bias[m], b1 = bias[m + 1], b2 = bias[m + 2], b3 = bias[m + 3];
#pragma unroll
        for (int j = 0; j < 2; j++) {
            const int n = n0 + wn * 32 + j * 16 + r15;
            ushort4 st;
            st.x = f2bf(fmaxf(acc[i][j][0] + b0, 0.f));
            st.y = f2bf(fmaxf(acc[i][j][1] + b1, 0.f));
            st.z = f2bf(fmaxf(acc[i][j][2] + b2, 0.f));
            st.w = f2bf(fmaxf(acc[i][j][3] + b3, 0.f));
            *(ushort4*)(tcf + (size_t)n * CC + m) = st;
        }
    }
}

// ---- heads1: wave-per-pixel, lane = 4-channel chunk (coalesced row read) ---
__global__ __launch_bounds__(256) void heads1_kernel(
    const unsigned short* __restrict__ tcf,
    const float* __restrict__ loc_w, const float* __restrict__ loc_b,
    const float* __restrict__ shape_w, const float* __restrict__ shape_b,
    float* __restrict__ out, float* __restrict__ s0s1)
{
    const int lane = threadIdx.x & 63, wv = threadIdx.x >> 6;
    const int n = blockIdx.x * 4 + wv;
    const int b = n / HWP, p = n - b * HWP;
    const int c = lane * 4;
    const ushort4 v = *(const ushort4*)(tcf + (size_t)n * CC + c);
    const float f0 = bf2f(v.x), f1 = bf2f(v.y), f2 = bf2f(v.z), f3 = bf2f(v.w);
    float aloc, s0, s1;
    aloc = loc_w[c] * f0;           aloc = fmaf(loc_w[c+1], f1, aloc);
    aloc = fmaf(loc_w[c+2], f2, aloc); aloc = fmaf(loc_w[c+3], f3, aloc);
    s0 = shape_w[c] * f0;           s0 = fmaf(shape_w[c+1], f1, s0);
    s0 = fmaf(shape_w[c+2], f2, s0);   s0 = fmaf(shape_w[c+3], f3, s0);
    s1 = shape_w[CC+c] * f0;        s1 = fmaf(shape_w[CC+c+1], f1, s1);
    s1 = fmaf(shape_w[CC+c+2], f2, s1); s1 = fmaf(shape_w[CC+c+3], f3, s1);
#pragma unroll
    for (int off = 32; off; off >>= 1) {
        aloc += __shfl_xor(aloc, off);
        s0   += __shfl_xor(s0, off);
        s1   += __shfl_xor(s1, off);
    }
    if (lane == 0) {
        const float l = aloc + loc_b[0], a = s0 + shape_b[0], cc2 = s1 + shape_b[1];
        out[OUT_LOC + n] = l;
        out[OUT_SHAPE + (b * 2 + 0) * HWP + p] = a;
        out[OUT_SHAPE + (b * 2 + 1) * HWP + p] = cc2;
        *(float2*)&s0s1[2 * n] = make_float2(a, cc2);
    }
}

// ---- fused GEMM2, split-K=2, M=256 x N=32, 256 thr / 4 waves ---------------
// R13: kh folded into blockIdx.x (bx&1) — the (kh=0,kh=1) pair of the same
// n0 dispatches adjacently (shared tcf neighborhood in same-XCD L2) and the
// full 4.5-blocks/CU grid co-fills in ONE pass (R12 y-dim ran kh serially).
// K-loop R11-exact: A-reg-prefetch (named-member struct), depth-1 sampler.
__global__ __launch_bounds__(256, 3) void gemm2_fused_kernel(
    const unsigned short* __restrict__ W2p, const unsigned short* __restrict__ tcf,
    const float* __restrict__ s0s1, const float* __restrict__ offset_w,
    float* __restrict__ pta0, float* __restrict__ pta1)
{
    __shared__ short Bs[2][2048];               // 2 x 4 KB (32 rows x 8 chunks, XOR)
    const int tid  = threadIdx.x;
    const int lane = tid & 63, wm = tid >> 6;   // 4 waves, wm = co-quarter (64 rows)
    const int quad = lane >> 4, r15 = lane & 15;
    const int kh  = blockIdx.x & 1;             // interleaved split-K half
    const int n0  = xcd_swizzle576(blockIdx.x >> 1) * 32;
    const int b   = n0 / HWP;                   // whole block in one batch
    const unsigned short* tb = tcf + (size_t)b * HWP * CC;

    // sampler mapping: thread -> pixel pr (0..31), 8-ch chunk kc (one px/thread)
    const int pr = tid >> 3, kc = tid & 7;
    const int xsw = (pr * 8 + (kc ^ (pr & 7))) * 8;   // Bs write slot (shorts)
    const int nb = n0 + pr;
    const int p  = nb - b * HWP;
    const int y = p / WW, x = p % WW;
    const float2 s01 = *(const float2*)&s0s1[2 * nb];

    f32x4 acc[4][2];
#pragma unroll
    for (int i = 0; i < 4; i++)
#pragma unroll
        for (int j = 0; j < 2; j++) acc[i][j] = (f32x4){0.f, 0.f, 0.f, 0.f};

    struct Samp { short8v v00, v01, v10, v11; float w00, w01, w10, w11; };
    struct AF2 { short8v c0i0, c0i1, c0i2, c0i3, c1i0, c1i1, c1i2, c1i3; };

    auto loadA = [&](int kt) -> AF2 {           // panel -> regs (L2-resident)
        const unsigned short* pnl = W2p + ((size_t)kt * 2048) * 8;
        const int b0 = quad * 256 + wm * 64 + r15;
        const int b1 = (4 + quad) * 256 + wm * 64 + r15;
        AF2 r;
        r.c0i0 = *(const short8v*)(pnl + (size_t)(b0 +  0) * 8);
        r.c0i1 = *(const short8v*)(pnl + (size_t)(b0 + 16) * 8);
        r.c0i2 = *(const short8v*)(pnl + (size_t)(b0 + 32) * 8);
        r.c0i3 = *(const short8v*)(pnl + (size_t)(b0 + 48) * 8);
        r.c1i0 = *(const short8v*)(pnl + (size_t)(b1 +  0) * 8);
        r.c1i1 = *(const short8v*)(pnl + (size_t)(b1 + 16) * 8);
        r.c1i2 = *(const short8v*)(pnl + (size_t)(b1 + 32) * 8);
        r.c1i3 = *(const short8v*)(pnl + (size_t)(b1 + 48) * 8);
        return r;
    };
    // issue phase: address math + 4 gathers into regs (R9-verbatim per-pixel math)
    auto sampIssue = [&](int kt) -> Samp {
        Samp s;
        const int kk = kt >> 2, g = kt & 3;
        const int o_dy = (g * 9 + kk) * 2, o_dx = o_dy + 1;
        const float dy = fmaf(offset_w[o_dy * 2], s01.x, offset_w[o_dy * 2 + 1] * s01.y);
        const float dx = fmaf(offset_w[o_dx * 2], s01.x, offset_w[o_dx * 2 + 1] * s01.y);
        const float py = (float)(y + kk / 3 - 1) + dy;
        const float px = (float)(x + kk % 3 - 1) + dx;
        const float y0f = floorf(py), x0f = floorf(px);
        const float wy = py - y0f, wx = px - x0f;
        const int y0 = (int)y0f, x0 = (int)x0f;
        const int y1 = y0 + 1, x1 = x0 + 1;
        const bool vy0 = (y0 >= 0) && (y0 < HH), vy1 = (y1 >= 0) && (y1 < HH);
        const bool vx0 = (x0 >= 0) && (x0 < WW), vx1 = (x1 >= 0) && (x1 < WW);
        const int y0c = min(max(y0, 0), HH - 1), y1c = min(max(y1, 0), HH - 1);
        const int x0c = min(max(x0, 0), WW - 1), x1c = min(max(x1, 0), WW - 1);
        s.w00 = (vy0 && vx0) ? (1.f - wy) * (1.f - wx) : 0.f;
        s.w01 = (vy0 && vx1) ? (1.f - wy) * wx         : 0.f;
        s.w10 = (vy1 && vx0) ? wy * (1.f - wx)         : 0.f;
        s.w11 = (vy1 && vx1) ? wy * wx                 : 0.f;
        const int ch = g * 64 + kc * 8;
        s.v00 = *(const short8v*)(tb + (size_t)(y0c * WW + x0c) * CC + ch);
        s.v01 = *(const short8v*)(tb + (size_t)(y0c * WW + x1c) * CC + ch);
        s.v10 = *(const short8v*)(tb + (size_t)(y1c * WW + x0c) * CC + ch);
        s.v11 = *(const short8v*)(tb + (size_t)(y1c * WW + x1c) * CC + ch);
        return s;
    };
    // finish phase: bilinear blend + bf16 round + swizzled ds_write
    auto sampFinish = [&](const Samp& s, int buf) {
        short8v r;
#pragma unroll
        for (int e = 0; e < 8; e++) {
            float val = s.w00 * bf2f((unsigned short)s.v00[e]);
            val = fmaf(s.w01, bf2f((unsigned short)s.v01[e]), val);
            val = fmaf(s.w10, bf2f((unsigned short)s.v10[e]), val);
            val = fmaf(s.w11, bf2f((unsigned short)s.v11[e]), val);
            r[e] = (short)f2bf(val);
        }
        *(short8v*)&Bs[buf][xsw] = r;
    };
    auto mma = [&](int buf, const AF2& a) {
        {   // ks = 0, kchunk = quad
            const int kchunk = quad;
            const int row0 = r15, row1 = 16 + r15;
            short8v bf0 = *(const short8v*)&Bs[buf][(row0 * 8 + (kchunk ^ (row0 & 7))) * 8];
            short8v bf1 = *(const short8v*)&Bs[buf][(row1 * 8 + (kchunk ^ (row1 & 7))) * 8];
            acc[0][0] = __builtin_amdgcn_mfma_f32_16x16x32_bf16(a.c0i0, bf0, acc[0][0], 0, 0, 0);
            acc[0][1] = __builtin_amdgcn_mfma_f32_16x16x32_bf16(a.c0i0, bf1, acc[0][1], 0, 0, 0);
            acc[1][0] = __builtin_amdgcn_mfma_f32_16x16x32_bf16(a.c0i1, bf0, acc[1][0], 0, 0, 0);
            acc[1][1] = __builtin_amdgcn_mfma_f32_16x16x32_bf16(a.c0i1, bf1, acc[1][1], 0, 0, 0);
            acc[2][0] = __builtin_amdgcn_mfma_f32_16x16x32_bf16(a.c0i2, bf0, acc[2][0], 0, 0, 0);
            acc[2][1] = __builtin_amdgcn_mfma_f32_16x16x32_bf16(a.c0i2, bf1, acc[2][1], 0, 0, 0);
            acc[3][0] = __builtin_amdgcn_mfma_f32_16x16x32_bf16(a.c0i3, bf0, acc[3][0], 0, 0, 0);
            acc[3][1] = __builtin_amdgcn_mfma_f32_16x16x32_bf16(a.c0i3, bf1, acc[3][1], 0, 0, 0);
        }
        {   // ks = 1, kchunk = 4 + quad
            const int kchunk = 4 + quad;
            const int row0 = r15, row1 = 16 + r15;
            short8v bf0 = *(const short8v*)&Bs[buf][(row0 * 8 + (kchunk ^ (row0 & 7))) * 8];
            short8v bf1 = *(const short8v*)&Bs[buf][(row1 * 8 + (kchunk ^ (row1 & 7))) * 8];
            acc[0][0] = __builtin_amdgcn_mfma_f32_16x16x32_bf16(a.c1i0, bf0, acc[0][0], 0, 0, 0);
            acc[0][1] = __builtin_amdgcn_mfma_f32_16x16x32_bf16(a.c1i0, bf1, acc[0][1], 0, 0, 0);
            acc[1][0] = __builtin_amdgcn_mfma_f32_16x16x32_bf16(a.c1i1, bf0, acc[1][0], 0, 0, 0);
            acc[1][1] = __builtin_amdgcn_mfma_f32_16x16x32_bf16(a.c1i1, bf1, acc[1][1], 0, 0, 0);
            acc[2][0] = __builtin_amdgcn_mfma_f32_16x16x32_bf16(a.c1i2, bf0, acc[2][0], 0, 0, 0);
            acc[2][1] = __builtin_amdgcn_mfma_f32_16x16x32_bf16(a.c1i2, bf1, acc[2][1], 0, 0, 0);
            acc[3][0] = __builtin_amdgcn_mfma_f32_16x16x32_bf16(a.c1i3, bf0, acc[3][0], 0, 0, 0);
            acc[3][1] = __builtin_amdgcn_mfma_f32_16x16x32_bf16(a.c1i3, bf1, acc[3][1], 0, 0, 0);
        }
    };

    const int kt0 = kh * KHS;
    AF2 afA = loadA(kt0), afB;
    { Samp s = sampIssue(kt0); sampFinish(s, 0); }
    __syncthreads();
    int cur = 0;
    // pairs for kt = kt0, kt0+2, ..., kt0+KHS-4
    for (int k2 = 0; k2 < (KHS - 2) / 2; k2++) {
        const int kt = kt0 + 2 * k2;
        {   // step kt: consume afA, prefetch afB = A(kt+1)
            const int nxt = cur ^ 1;
            afB = loadA(kt + 1);
            Samp s = sampIssue(kt + 1);
            mma(cur, afA);
            sampFinish(s, nxt);
            __syncthreads();
            cur = nxt;
        }
        {   // step kt+1: consume afB, prefetch afA = A(kt+2)
            const int nxt = cur ^ 1;
            afA = loadA(kt + 2);
            Samp s = sampIssue(kt + 2);
            mma(cur, afB);
            sampFinish(s, nxt);
            __syncthreads();
            cur = nxt;
        }
    }
    {   // step kt0+KHS-2: consume afA, prefetch afB
        const int nxt = cur ^ 1;
        afB = loadA(kt0 + KHS - 1);
        Samp s = sampIssue(kt0 + KHS - 1);
        mma(cur, afA);
        sampFinish(s, nxt);
        __syncthreads();
        cur = nxt;
    }
    mma(cur, afB);                              // step kt0+KHS-1

    // epilogue: fp32 partial (no relu), n-major [n][c]
    float* pta = kh ? pta1 : pta0;
#pragma unroll
    for (int i = 0; i < 4; i++) {
        const int m = wm * 64 + i * 16 + quad * 4;
#pragma unroll
        for (int j = 0; j < 2; j++) {
            const int n = n0 + j * 16 + r15;
            float4 st;
            st.x = acc[i][j][0];
            st.y = acc[i][j][1];
            st.z = acc[i][j][2];
            st.w = acc[i][j][3];
            *(float4*)(pta + (size_t)n * CC + m) = st;
        }
    }
}

// ---- heads2: wave-per-pixel cls/bbox dots on relu(pta0+pta1), n-major ------
__global__ __launch_bounds__(256) void heads2_kernel(
    const float* __restrict__ pta0, const float* __restrict__ pta1,
    const float* __restrict__ cls_w, const float* __restrict__ cls_b,
    const float* __restrict__ bbox_w, const float* __restrict__ bbox_b,
    float* __restrict__ out)
{
    const int lane = threadIdx.x & 63, wv = threadIdx.x >> 6;
    const int n = blockIdx.x * 4 + wv;
    const int b = n / HWP, p = n - b * HWP;
    const int c = lane * 4;
    const float4 v0 = *(const float4*)(pta0 + (size_t)n * CC + c);
    const float4 v1 = *(const float4*)(pta1 + (size_t)n * CC + c);
    float4 v;
    v.x = fmaxf(v0.x + v1.x, 0.f);
    v.y = fmaxf(v0.y + v1.y, 0.f);
    v.z = fmaxf(v0.z + v1.z, 0.f);
    v.w = fmaxf(v0.w + v1.w, 0.f);
    float ac, a0, a1, a2, a3;
    ac = cls_w[c] * v.x;              ac = fmaf(cls_w[c+1], v.y, ac);
    ac = fmaf(cls_w[c+2], v.z, ac);   ac = fmaf(cls_w[c+3], v.w, ac);
    a0 = bbox_w[c] * v.x;             a0 = fmaf(bbox_w[c+1], v.y, a0);
    a0 = fmaf(bbox_w[c+2], v.z, a0);  a0 = fmaf(bbox_w[c+3], v.w, a0);
    a1 = bbox_w[CC+c] * v.x;          a1 = fmaf(bbox_w[CC+c+1], v.y, a1);
    a1 = fmaf(bbox_w[CC+c+2], v.z, a1); a1 = fmaf(bbox_w[CC+c+3], v.w, a1);
    a2 = bbox_w[2*CC+c] * v.x;        a2 = fmaf(bbox_w[2*CC+c+1], v.y, a2);
    a2 = fmaf(bbox_w[2*CC+c+2], v.z, a2); a2 = fmaf(bbox_w[2*CC+c+3], v.w, a2);
    a3 = bbox_w[3*CC+c] * v.x;        a3 = fmaf(bbox_w[3*CC+c+1], v.y, a3);
    a3 = fmaf(bbox_w[3*CC+c+2], v.z, a3); a3 = fmaf(bbox_w[3*CC+c+3], v.w, a3);
#pragma unroll
    for (int off = 32; off; off >>= 1) {
        ac += __shfl_xor(ac, off);
        a0 += __shfl_xor(a0, off);
        a1 += __shfl_xor(a1, off);
        a2 += __shfl_xor(a2, off);
        a3 += __shfl_xor(a3, off);
    }
    if (lane == 0) {
        out[OUT_LOGITS + n] = ac + cls_b[0];
        out[OUT_BBOX + (b * 4 + 0) * HWP + p] = a0 + bbox_b[0];
        out[OUT_BBOX + (b * 4 + 1) * HWP + p] = a1 + bbox_b[1];
        out[OUT_BBOX + (b * 4 + 2) * HWP + p] = a2 + bbox_b[2];
        out[OUT_BBOX + (b * 4 + 3) * HWP + p] = a3 + bbox_b[3];
    }
}

// ----------------------------------------------------------------------------
extern "C" void kernel_launch(void* const* d_in, const int* in_sizes, int n_in,
                              void* d_out, int out_size, void* d_ws, size_t ws_size,
                              hipStream_t stream)
{
    const float* feature  = (const float*)d_in[0];
    const float* conv_w   = (const float*)d_in[1];
    const float* conv_b   = (const float*)d_in[2];
    const float* loc_w    = (const float*)d_in[3];
    const float* loc_b    = (const float*)d_in[4];
    const float* shape_w  = (const float*)d_in[5];
    const float* shape_b  = (const float*)d_in[6];
    const float* offset_w = (const float*)d_in[7];
    const float* adapt_w  = (const float*)d_in[8];
    const float* cls_w    = (const float*)d_in[9];
    const float* cls_b    = (const float*)d_in[10];
    const float* bbox_w   = (const float*)d_in[11];
    const float* bbox_b   = (const float*)d_in[12];
    float* out = (float*)d_out;

    // workspace partition (~59 MB)
    float*          s0s1 = (float*)d_ws;                           // NTOT float2
    unsigned short* tcf  = (unsigned short*)(s0s1 + 2 * NTOT);     // NTOT*CC bf16
    unsigned short* fcf  = tcf + (size_t)NTOT * CC;                // NTOT*CC bf16
    unsigned short* W1p  = fcf + (size_t)NTOT * CC;                // CC*K1 bf16 (panels)
    unsigned short* W2p  = W1p + (size_t)CC * K1;                  // CC*K1 bf16 (panels)
    unsigned short* zp   = W2p + (size_t)CC * K1;                  // 1024 zeros
    float*          pta0 = (float*)(zp + 1024);                    // NTOT x CC fp32 (n-major)
    float*          pta1 = pta0 + (size_t)NTOT * CC;               // NTOT x CC fp32 (n-major)

    prep_kernel<<<(CC * K1 + 255) / 256, 256, 0, stream>>>(conv_w, adapt_w, W1p, W2p, zp);
    transpose_kernel<<<dim3(HWP / 64, 4, BB), 256, 0, stream>>>(feature, fcf);
    gemm1_kernel<<<dim3(NTOT / 64 * 2), 512, 0, stream>>>(W1p, fcf, conv_b, zp, tcf);
    heads1_kernel<<<dim3(NTOT / 4), 256, 0, stream>>>(
        tcf, loc_w, loc_b, shape_w, shape_b, out, s0s1);
    gemm2_fused_kernel<<<dim3(NTOT / 32 * 2), 256, 0, stream>>>(
        W2p, tcf, s0s1, offset_w, pta0, pta1);
    heads2_kernel<<<dim3(NTOT / 4), 256, 0, stream>>>(
        pta0, pta1, cls_w, cls_b, bbox_w, bbox_b, out);
}

// Round 14
// 192.582 us; speedup vs baseline: 1.0122x; 1.0122x over previous
//
#include <hip/hip_runtime.h>
#include <hip/hip_bf16.h>

// Problem constants
#define BB 2
#define CC 256
#define HH 96
#define WW 96
#define HWP (HH*WW)        // 9216
#define NTOT (BB*HWP)      // 18432 flattened (b,p)
#define K1 2304            // 256*9, GEMM K for both convs
#define NKT 36             // K1/64 k-steps

// d_out layout: logits[2,1,96,96], bbox[2,4,96,96], shape[2,2,96,96], loc[2,1,96,96]
#define OUT_LOGITS 0
#define OUT_BBOX   (2*1*HWP)
#define OUT_SHAPE  (OUT_BBOX + 2*4*HWP)
#define OUT_LOC    (OUT_SHAPE + 2*2*HWP)

typedef __attribute__((ext_vector_type(8))) short short8v;   // 8 bf16 (4 VGPRs)
typedef __attribute__((ext_vector_type(4))) float f32x4;

// XCD-aware swizzles: contiguous slab of consecutive n-blocks per XCD.
__device__ __forceinline__ int xcd_swizzle288(int bx) {   // 288 = 8 x 36
    return (bx & 7) * 36 + (bx >> 3);
}
__device__ __forceinline__ int xcd_swizzle576(int bx) {   // 576 = 8 x 72
    return (bx & 7) * 72 + (bx >> 3);
}

__device__ __forceinline__ float bf2f(unsigned short u) {
    return __uint_as_float(((unsigned)u) << 16);
}
__device__ __forceinline__ unsigned short f2bf(float f) {
    unsigned u = __float_as_uint(f);
    u += 0x7FFFu + ((u >> 16) & 1u);           // round-to-nearest-even
    return (unsigned short)(u >> 16);
}

// ------- prep: weights -> bf16 PRE-SWIZZLED A panels + zero page ------------
__global__ __launch_bounds__(256) void prep_kernel(
    const float* __restrict__ conv_w, const float* __restrict__ adapt_w,
    unsigned short* __restrict__ W1p, unsigned short* __restrict__ W2p,
    unsigned short* __restrict__ zp)
{
    const int t = blockIdx.x * 256 + threadIdx.x;
    if (t < 1024) zp[t] = 0;                    // zero page (ws is re-poisoned!)
    if (t < CC * K1) {
        const int e = t & 7;
        {   // W1p
            const int s  = (t >> 3) & 1023;
            const int r  = t >> 13;             // cb*36+kt, [0,72)
            const int kt = r % 36, cb = r / 36;
            const int row = s & 127, kc = s >> 7;
            const int co = cb * 128 + row;
            const int k  = kt * 64 + kc * 8 + e;
            const int kk = k >> 8, ci = k & 255;
            W1p[t] = f2bf(conv_w[co * K1 + ci * 9 + kk]);
        }
        {   // W2p
            const int s  = (t >> 3) & 2047;
            const int kt = t >> 14;             // [0,36)
            const int row = s & 255, kc = s >> 8;
            const int k  = kt * 64 + kc * 8 + e;
            const int kk = k >> 8, ci = k & 255;
            W2p[t] = f2bf(adapt_w[row * K1 + ci * 9 + kk]);
        }
    }
}

// ------------- transpose feature [b][c][p] fp32 -> f_cf [b][p][c] bf16 ------
// R12: store phase vectorized to ushort4 (512 B/wave-instr vs 128 B scalar).
__global__ __launch_bounds__(256) void transpose_kernel(
    const float* __restrict__ f, unsigned short* __restrict__ fcf)
{
    __shared__ unsigned short tile[64][66];     // +2 pad
    const int p0 = blockIdx.x * 64;
    const int cc = blockIdx.y;
    const int b  = blockIdx.z;
    const int tx = threadIdx.x & 63, ty = threadIdx.x >> 6;
#pragma unroll
    for (int ii = 0; ii < 16; ii++) {
        const int cl = ii * 4 + ty;
        tile[cl][tx] = f2bf(f[((size_t)b * CC + cc * 64 + cl) * HWP + p0 + tx]);
    }
    __syncthreads();
    const int tx4 = threadIdx.x & 15;           // c-quad index (c = tx4*4..+3)
    const int py  = threadIdx.x >> 4;           // pixel sub-index (0..15)
#pragma unroll
    for (int ii = 0; ii < 4; ii++) {
        const int pl = ii * 16 + py;
        ushort4 v;
        v.x = tile[tx4 * 4 + 0][pl];
        v.y = tile[tx4 * 4 + 1][pl];
        v.z = tile[tx4 * 4 + 2][pl];
        v.w = tile[tx4 * 4 + 3][pl];
        *(ushort4*)(fcf + ((size_t)(b * HWP + p0 + pl)) * CC + cc * 64 + tx4 * 4) = v;
    }
}

// --------- GEMM1: t = relu(W1 x im2col + bias), 512 thr / 8 waves -----------
// M=128 x N=64, BK=64. R13: cb folded into blockIdx.x (bx&1). K-loop
// R9-exact: A-direct from L2-resident W1p, depth-1 B prefetch.
__global__ __launch_bounds__(512, 6) void gemm1_kernel(
    const unsigned short* __restrict__ W1p, const unsigned short* __restrict__ fcf,
    const float* __restrict__ bias, const unsigned short* __restrict__ zp,
    unsigned short* __restrict__ tcf)
{
    __shared__ short Bs[2][4096];               // 2 x 8 KB (XOR-swizzled)
    const int tid  = threadIdx.x;
    const int lane = tid & 63, w = tid >> 6;    // w in [0,8)
    const int quad = lane >> 4, r15 = lane & 15;
    const int cb  = blockIdx.x & 1;             // interleaved co-half
    const int n0  = xcd_swizzle288(blockIdx.x >> 1) * 64;
    const int co0 = cb * 128;
    const int wm = w & 3, wn = w >> 2;          // co-quarter (32 rows), n-half

    // B staging geometry: thread -> (pixel pr, 8-ch chunk kc)
    const int pr = tid >> 3, kc = tid & 7;
    const int xsw = (pr * 8 + (kc ^ (pr & 7))) * 8;   // Bs write slot (shorts)
    const int nb = n0 + pr;
    const int b  = nb / HWP;
    const int p  = nb - b * HWP;
    const int y = p / WW, x = p % WW;
    const unsigned short* fb = fcf + (size_t)b * HWP * CC;

    f32x4 acc[2][2];
#pragma unroll
    for (int i = 0; i < 2; i++)
#pragma unroll
        for (int j = 0; j < 2; j++) acc[i][j] = (f32x4){0.f, 0.f, 0.f, 0.f};

    auto loadB = [&](int kt) -> short8v {
        const int kk  = kt >> 2;
        const int ci0 = (kt & 3) * 64;
        const int yy = y + kk / 3 - 1, xx = x + kk % 3 - 1;
        const bool ok = (yy >= 0) && (yy < HH) && (xx >= 0) && (xx < WW);
        const unsigned short* src = ok
            ? fb + (size_t)(yy * WW + xx) * CC + ci0 + kc * 8
            : zp;
        return *(const short8v*)src;
    };
    // A-fragment direct from global: slot = kchunk*128 + row within kt-panel.
    auto mma = [&](int buf, int kt) {
        const unsigned short* pnl = W1p + ((size_t)(cb * 36 + kt) * 1024) * 8;
#pragma unroll
        for (int ks = 0; ks < 2; ks++) {
            short8v a[2], bf[2];
            const int kchunk = ks * 4 + quad;
#pragma unroll
            for (int i = 0; i < 2; i++)
                a[i] = *(const short8v*)(pnl + (size_t)(kchunk * 128 + wm * 32 + i * 16 + r15) * 8);
#pragma unroll
            for (int j = 0; j < 2; j++) {
                const int row = wn * 32 + j * 16 + r15;
                bf[j] = *(const short8v*)&Bs[buf][(row * 8 + (kchunk ^ (row & 7))) * 8];
            }
#pragma unroll
            for (int i = 0; i < 2; i++)
#pragma unroll
                for (int j = 0; j < 2; j++)
                    acc[i][j] = __builtin_amdgcn_mfma_f32_16x16x32_bf16(a[i], bf[j], acc[i][j], 0, 0, 0);
        }
    };

    { short8v b0 = loadB(0); *(short8v*)&Bs[0][xsw] = b0; }
    __syncthreads();
    int cur = 0;
    for (int kt = 0; kt < NKT - 1; kt++) {
        const int nxt = cur ^ 1;
        short8v bn = loadB(kt + 1);             // -> regs, latency under MFMA
        mma(cur, kt);
        *(short8v*)&Bs[nxt][xsw] = bn;
        __syncthreads();
        cur = nxt;
    }
    mma(cur, NKT - 1);                          // peeled last tile

    // epilogue: bias + relu -> t_cf[n][c] bf16 (C/D map: col=lane&15, row=quad*4+reg)
#pragma unroll
    for (int i = 0; i < 2; i++) {
        const int m = co0 + wm * 32 + i * 16 + quad * 4;
        const float b0 = bias[m], b1 = bias[m + 1], b2 = bias[m + 2], b3 = bias[m + 3];
#pragma unroll
        for (int j = 0; j < 2; j++) {
            const int n = n0 + wn * 32 + j * 16 + r15;
            ushort4 st;
            st.x = f2bf(fmaxf(acc[i][j][0] + b0, 0.f));
            st.y = f2bf(fmaxf(acc[i][j][1] + b1, 0.f));
            st.z = f2bf(fmaxf(acc[i][j][2] + b2, 0.f));
            st.w = f2bf(fmaxf(acc[i][j][3] + b3, 0.f));
            *(ushort4*)(tcf + (size_t)n * CC + m) = st;
        }
    }
}

// ---- heads1: wave-per-pixel, lane = 4-channel chunk (coalesced row read) ---
__global__ __launch_bounds__(256) void heads1_kernel(
    const unsigned short* __restrict__ tcf,
    const float* __restrict__ loc_w, const float* __restrict__ loc_b,
    const float* __restrict__ shape_w, const float* __restrict__ shape_b,
    float* __restrict__ out, float* __restrict__ s0s1)
{
    const int lane = threadIdx.x & 63, wv = threadIdx.x >> 6;
    const int n = blockIdx.x * 4 + wv;
    const int b = n / HWP, p = n - b * HWP;
    const int c = lane * 4;
    const ushort4 v = *(const ushort4*)(tcf + (size_t)n * CC + c);
    const float f0 = bf2f(v.x), f1 = bf2f(v.y), f2 = bf2f(v.z), f3 = bf2f(v.w);
    float aloc, s0, s1;
    aloc = loc_w[c] * f0;           aloc = fmaf(loc_w[c+1], f1, aloc);
    aloc = fmaf(loc_w[c+2], f2, aloc); aloc = fmaf(loc_w[c+3], f3, aloc);
    s0 = shape_w[c] * f0;           s0 = fmaf(shape_w[c+1], f1, s0);
    s0 = fmaf(shape_w[c+2], f2, s0);   s0 = fmaf(shape_w[c+3], f3, s0);
    s1 = shape_w[CC+c] * f0;        s1 = fmaf(shape_w[CC+c+1], f1, s1);
    s1 = fmaf(shape_w[CC+c+2], f2, s1); s1 = fmaf(shape_w[CC+c+3], f3, s1);
#pragma unroll
    for (int off = 32; off; off >>= 1) {
        aloc += __shfl_xor(aloc, off);
        s0   += __shfl_xor(s0, off);
        s1   += __shfl_xor(s1, off);
    }
    if (lane == 0) {
        const float l = aloc + loc_b[0], a = s0 + shape_b[0], cc2 = s1 + shape_b[1];
        out[OUT_LOC + n] = l;
        out[OUT_SHAPE + (b * 2 + 0) * HWP + p] = a;
        out[OUT_SHAPE + (b * 2 + 1) * HWP + p] = cc2;
        *(float2*)&s0s1[2 * n] = make_float2(a, cc2);
    }
}

// ---- fused GEMM2 + heads2, FULL-K, M=256 x N=32, 256 thr / 4 waves ---------
// R14: split-K removed; each block holds the COMPLETE 256-ch ta for its 32
// pixels in registers, so cls/bbox heads fuse into the epilogue (relu in-reg
// -> per-thread 16-ch partial dots -> quad-shuffle -> LDS cross-wave reduce
// -> 6 floats/pixel). Eliminates pta (36.9 MB write) and heads2 (73.7 MB
// read). K-loop R13-exact (A-reg-prefetch named-struct, depth-1 sampler),
// kt range 0..35. Full-K accumulation order = R6/R7-proven.
__global__ __launch_bounds__(256, 3) void gemm2_fused_kernel(
    const unsigned short* __restrict__ W2p, const unsigned short* __restrict__ tcf,
    const float* __restrict__ s0s1, const float* __restrict__ offset_w,
    const float* __restrict__ cls_w, const float* __restrict__ cls_b,
    const float* __restrict__ bbox_w, const float* __restrict__ bbox_b,
    float* __restrict__ out)
{
    __shared__ short Bs[2][2048];               // 2 x 4 KB (32 rows x 8 chunks, XOR)
    __shared__ float sm[4][32][6];              // [wave][n][5 heads], +1 pad
    const int tid  = threadIdx.x;
    const int lane = tid & 63, wm = tid >> 6;   // 4 waves, wm = co-quarter (64 rows)
    const int quad = lane >> 4, r15 = lane & 15;
    const int n0  = xcd_swizzle576(blockIdx.x) * 32;
    const int b   = n0 / HWP;                   // whole block in one batch
    const unsigned short* tb = tcf + (size_t)b * HWP * CC;

    // sampler mapping: thread -> pixel pr (0..31), 8-ch chunk kc (one px/thread)
    const int pr = tid >> 3, kc = tid & 7;
    const int xsw = (pr * 8 + (kc ^ (pr & 7))) * 8;   // Bs write slot (shorts)
    const int nb = n0 + pr;
    const int p  = nb - b * HWP;
    const int y = p / WW, x = p % WW;
    const float2 s01 = *(const float2*)&s0s1[2 * nb];

    f32x4 acc[4][2];
#pragma unroll
    for (int i = 0; i < 4; i++)
#pragma unroll
        for (int j = 0; j < 2; j++) acc[i][j] = (f32x4){0.f, 0.f, 0.f, 0.f};

    struct Samp { short8v v00, v01, v10, v11; float w00, w01, w10, w11; };
    struct AF2 { short8v c0i0, c0i1, c0i2, c0i3, c1i0, c1i1, c1i2, c1i3; };

    auto loadA = [&](int kt) -> AF2 {           // panel -> regs (L2-resident)
        const unsigned short* pnl = W2p + ((size_t)kt * 2048) * 8;
        const int b0 = quad * 256 + wm * 64 + r15;
        const int b1 = (4 + quad) * 256 + wm * 64 + r15;
        AF2 r;
        r.c0i0 = *(const short8v*)(pnl + (size_t)(b0 +  0) * 8);
        r.c0i1 = *(const short8v*)(pnl + (size_t)(b0 + 16) * 8);
        r.c0i2 = *(const short8v*)(pnl + (size_t)(b0 + 32) * 8);
        r.c0i3 = *(const short8v*)(pnl + (size_t)(b0 + 48) * 8);
        r.c1i0 = *(const short8v*)(pnl + (size_t)(b1 +  0) * 8);
        r.c1i1 = *(const short8v*)(pnl + (size_t)(b1 + 16) * 8);
        r.c1i2 = *(const short8v*)(pnl + (size_t)(b1 + 32) * 8);
        r.c1i3 = *(const short8v*)(pnl + (size_t)(b1 + 48) * 8);
        return r;
    };
    // issue phase: address math + 4 gathers into regs (R9-verbatim per-pixel math)
    auto sampIssue = [&](int kt) -> Samp {
        Samp s;
        const int kk = kt >> 2, g = kt & 3;
        const int o_dy = (g * 9 + kk) * 2, o_dx = o_dy + 1;
        const float dy = fmaf(offset_w[o_dy * 2], s01.x, offset_w[o_dy * 2 + 1] * s01.y);
        const float dx = fmaf(offset_w[o_dx * 2], s01.x, offset_w[o_dx * 2 + 1] * s01.y);
        const float py = (float)(y + kk / 3 - 1) + dy;
        const float px = (float)(x + kk % 3 - 1) + dx;
        const float y0f = floorf(py), x0f = floorf(px);
        const float wy = py - y0f, wx = px - x0f;
        const int y0 = (int)y0f, x0 = (int)x0f;
        const int y1 = y0 + 1, x1 = x0 + 1;
        const bool vy0 = (y0 >= 0) && (y0 < HH), vy1 = (y1 >= 0) && (y1 < HH);
        const bool vx0 = (x0 >= 0) && (x0 < WW), vx1 = (x1 >= 0) && (x1 < WW);
        const int y0c = min(max(y0, 0), HH - 1), y1c = min(max(y1, 0), HH - 1);
        const int x0c = min(max(x0, 0), WW - 1), x1c = min(max(x1, 0), WW - 1);
        s.w00 = (vy0 && vx0) ? (1.f - wy) * (1.f - wx) : 0.f;
        s.w01 = (vy0 && vx1) ? (1.f - wy) * wx         : 0.f;
        s.w10 = (vy1 && vx0) ? wy * (1.f - wx)         : 0.f;
        s.w11 = (vy1 && vx1) ? wy * wx                 : 0.f;
        const int ch = g * 64 + kc * 8;
        s.v00 = *(const short8v*)(tb + (size_t)(y0c * WW + x0c) * CC + ch);
        s.v01 = *(const short8v*)(tb + (size_t)(y0c * WW + x1c) * CC + ch);
        s.v10 = *(const short8v*)(tb + (size_t)(y1c * WW + x0c) * CC + ch);
        s.v11 = *(const short8v*)(tb + (size_t)(y1c * WW + x1c) * CC + ch);
        return s;
    };
    // finish phase: bilinear blend + bf16 round + swizzled ds_write
    auto sampFinish = [&](const Samp& s, int buf) {
        short8v r;
#pragma unroll
        for (int e = 0; e < 8; e++) {
            float val = s.w00 * bf2f((unsigned short)s.v00[e]);
            val = fmaf(s.w01, bf2f((unsigned short)s.v01[e]), val);
            val = fmaf(s.w10, bf2f((unsigned short)s.v10[e]), val);
            val = fmaf(s.w11, bf2f((unsigned short)s.v11[e]), val);
            r[e] = (short)f2bf(val);
        }
        *(short8v*)&Bs[buf][xsw] = r;
    };
    auto mma = [&](int buf, const AF2& a) {
        {   // ks = 0, kchunk = quad
            const int kchunk = quad;
            const int row0 = r15, row1 = 16 + r15;
            short8v bf0 = *(const short8v*)&Bs[buf][(row0 * 8 + (kchunk ^ (row0 & 7))) * 8];
            short8v bf1 = *(const short8v*)&Bs[buf][(row1 * 8 + (kchunk ^ (row1 & 7))) * 8];
            acc[0][0] = __builtin_amdgcn_mfma_f32_16x16x32_bf16(a.c0i0, bf0, acc[0][0], 0, 0, 0);
            acc[0][1] = __builtin_amdgcn_mfma_f32_16x16x32_bf16(a.c0i0, bf1, acc[0][1], 0, 0, 0);
            acc[1][0] = __builtin_amdgcn_mfma_f32_16x16x32_bf16(a.c0i1, bf0, acc[1][0], 0, 0, 0);
            acc[1][1] = __builtin_amdgcn_mfma_f32_16x16x32_bf16(a.c0i1, bf1, acc[1][1], 0, 0, 0);
            acc[2][0] = __builtin_amdgcn_mfma_f32_16x16x32_bf16(a.c0i2, bf0, acc[2][0], 0, 0, 0);
            acc[2][1] = __builtin_amdgcn_mfma_f32_16x16x32_bf16(a.c0i2, bf1, acc[2][1], 0, 0, 0);
            acc[3][0] = __builtin_amdgcn_mfma_f32_16x16x32_bf16(a.c0i3, bf0, acc[3][0], 0, 0, 0);
            acc[3][1] = __builtin_amdgcn_mfma_f32_16x16x32_bf16(a.c0i3, bf1, acc[3][1], 0, 0, 0);
        }
        {   // ks = 1, kchunk = 4 + quad
            const int kchunk = 4 + quad;
            const int row0 = r15, row1 = 16 + r15;
            short8v bf0 = *(const short8v*)&Bs[buf][(row0 * 8 + (kchunk ^ (row0 & 7))) * 8];
            short8v bf1 = *(const short8v*)&Bs[buf][(row1 * 8 + (kchunk ^ (row1 & 7))) * 8];
            acc[0][0] = __builtin_amdgcn_mfma_f32_16x16x32_bf16(a.c1i0, bf0, acc[0][0], 0, 0, 0);
            acc[0][1] = __builtin_amdgcn_mfma_f32_16x16x32_bf16(a.c1i0, bf1, acc[0][1], 0, 0, 0);
            acc[1][0] = __builtin_amdgcn_mfma_f32_16x16x32_bf16(a.c1i1, bf0, acc[1][0], 0, 0, 0);
            acc[1][1] = __builtin_amdgcn_mfma_f32_16x16x32_bf16(a.c1i1, bf1, acc[1][1], 0, 0, 0);
            acc[2][0] = __builtin_amdgcn_mfma_f32_16x16x32_bf16(a.c1i2, bf0, acc[2][0], 0, 0, 0);
            acc[2][1] = __builtin_amdgcn_mfma_f32_16x16x32_bf16(a.c1i2, bf1, acc[2][1], 0, 0, 0);
            acc[3][0] = __builtin_amdgcn_mfma_f32_16x16x32_bf16(a.c1i3, bf0, acc[3][0], 0, 0, 0);
            acc[3][1] = __builtin_amdgcn_mfma_f32_16x16x32_bf16(a.c1i3, bf1, acc[3][1], 0, 0, 0);
        }
    };

    // ---- K-loop over all 36 kts (full-K), R13 structure ----
    AF2 afA = loadA(0), afB;
    { Samp s = sampIssue(0); sampFinish(s, 0); }
    __syncthreads();
    int cur = 0;
    // 17 pairs cover steps 0..33, prefetching tiles 1..34
    for (int k2 = 0; k2 < (NKT - 2) / 2; k2++) {
        const int kt = 2 * k2;
        {   // step kt: consume afA, prefetch afB = A(kt+1)
            const int nxt = cur ^ 1;
            afB = loadA(kt + 1);
            Samp s = sampIssue(kt + 1);
            mma(cur, afA);
            sampFinish(s, nxt);
            __syncthreads();
            cur = nxt;
        }
        {   // step kt+1: consume afB, prefetch afA = A(kt+2)
            const int nxt = cur ^ 1;
            afA = loadA(kt + 2);
            Samp s = sampIssue(kt + 2);
            mma(cur, afB);
            sampFinish(s, nxt);
            __syncthreads();
            cur = nxt;
        }
    }
    {   // step NKT-2 = 34: consume afA, prefetch afB = A(35)
        const int nxt = cur ^ 1;
        afB = loadA(NKT - 1);
        Samp s = sampIssue(NKT - 1);
        mma(cur, afA);
        sampFinish(s, nxt);
        __syncthreads();
        cur = nxt;
    }
    mma(cur, afB);                              // step 35

    // ---- fused epilogue: relu + cls/bbox dots, cross-wave reduce ----
    // Per-thread: 16 co-channels (4 i-blocks x 4 regs) at 2 n-slots (j).
    float pc[2]  = {0.f, 0.f};
    float pb0[2] = {0.f, 0.f}, pb1[2] = {0.f, 0.f};
    float pb2[2] = {0.f, 0.f}, pb3[2] = {0.f, 0.f};
#pragma unroll
    for (int i = 0; i < 4; i++) {
        const int m = wm * 64 + i * 16 + quad * 4;
        const float4 cw  = *(const float4*)(cls_w + m);
        const float4 b0w = *(const float4*)(bbox_w + m);
        const float4 b1w = *(const float4*)(bbox_w + CC + m);
        const float4 b2w = *(const float4*)(bbox_w + 2 * CC + m);
        const float4 b3w = *(const float4*)(bbox_w + 3 * CC + m);
#pragma unroll
        for (int j = 0; j < 2; j++) {
            const float t0 = fmaxf(acc[i][j][0], 0.f);
            const float t1 = fmaxf(acc[i][j][1], 0.f);
            const float t2 = fmaxf(acc[i][j][2], 0.f);
            const float t3 = fmaxf(acc[i][j][3], 0.f);
            pc[j]  = fmaf(cw.x,  t0, fmaf(cw.y,  t1, fmaf(cw.z,  t2, fmaf(cw.w,  t3, pc[j]))));
            pb0[j] = fmaf(b0w.x, t0, fmaf(b0w.y, t1, fmaf(b0w.z, t2, fmaf(b0w.w, t3, pb0[j]))));
            pb1[j] = fmaf(b1w.x, t0, fmaf(b1w.y, t1, fmaf(b1w.z, t2, fmaf(b1w.w, t3, pb1[j]))));
            pb2[j] = fmaf(b2w.x, t0, fmaf(b2w.y, t1, fmaf(b2w.z, t2, fmaf(b2w.w, t3, pb2[j]))));
            pb3[j] = fmaf(b3w.x, t0, fmaf(b3w.y, t1, fmaf(b3w.z, t2, fmaf(b3w.w, t3, pb3[j]))));
        }
    }
    // reduce across quad (lanes r15 + 16*quad): xor 16, 32 sums all 4 quads
#pragma unroll
    for (int j = 0; j < 2; j++) {
#pragma unroll
        for (int off = 16; off <= 32; off <<= 1) {
            pc[j]  += __shfl_xor(pc[j],  off);
            pb0[j] += __shfl_xor(pb0[j], off);
            pb1[j] += __shfl_xor(pb1[j], off);
            pb2[j] += __shfl_xor(pb2[j], off);
            pb3[j] += __shfl_xor(pb3[j], off);
        }
    }
    if (quad == 0) {                            // lanes 0..15 hold reduced vals
#pragma unroll
        for (int j = 0; j < 2; j++) {
            const int nl = j * 16 + r15;
            sm[wm][nl][0] = pc[j];
            sm[wm][nl][1] = pb0[j];
            sm[wm][nl][2] = pb1[j];
            sm[wm][nl][3] = pb2[j];
            sm[wm][nl][4] = pb3[j];
        }
    }
    __syncthreads();
    if (tid < 32) {                             // one thread per pixel
        const int n = n0 + tid;
        const int bb = n / HWP, pp = n - bb * HWP;
        const float vc = sm[0][tid][0] + sm[1][tid][0] + sm[2][tid][0] + sm[3][tid][0];
        const float v0 = sm[0][tid][1] + sm[1][tid][1] + sm[2][tid][1] + sm[3][tid][1];
        const float v1 = sm[0][tid][2] + sm[1][tid][2] + sm[2][tid][2] + sm[3][tid][2];
        const float v2 = sm[0][tid][3] + sm[1][tid][3] + sm[2][tid][3] + sm[3][tid][3];
        const float v3 = sm[0][tid][4] + sm[1][tid][4] + sm[2][tid][4] + sm[3][tid][4];
        out[OUT_LOGITS + n] = vc + cls_b[0];
        out[OUT_BBOX + (bb * 4 + 0) * HWP + pp] = v0 + bbox_b[0];
        out[OUT_BBOX + (bb * 4 + 1) * HWP + pp] = v1 + bbox_b[1];
        out[OUT_BBOX + (bb * 4 + 2) * HWP + pp] = v2 + bbox_b[2];
        out[OUT_BBOX + (bb * 4 + 3) * HWP + pp] = v3 + bbox_b[3];
    }
}

// ----------------------------------------------------------------------------
extern "C" void kernel_launch(void* const* d_in, const int* in_sizes, int n_in,
                              void* d_out, int out_size, void* d_ws, size_t ws_size,
                              hipStream_t stream)
{
    const float* feature  = (const float*)d_in[0];
    const float* conv_w   = (const float*)d_in[1];
    const float* conv_b   = (const float*)d_in[2];
    const float* loc_w    = (const float*)d_in[3];
    const float* loc_b    = (const float*)d_in[4];
    const float* shape_w  = (const float*)d_in[5];
    const float* shape_b  = (const float*)d_in[6];
    const float* offset_w = (const float*)d_in[7];
    const float* adapt_w  = (const float*)d_in[8];
    const float* cls_w    = (const float*)d_in[9];
    const float* cls_b    = (const float*)d_in[10];
    const float* bbox_w   = (const float*)d_in[11];
    const float* bbox_b   = (const float*)d_in[12];
    float* out = (float*)d_out;

    // workspace partition (~22 MB — pta eliminated)
    float*          s0s1 = (float*)d_ws;                           // NTOT float2
    unsigned short* tcf  = (unsigned short*)(s0s1 + 2 * NTOT);     // NTOT*CC bf16
    unsigned short* fcf  = tcf + (size_t)NTOT * CC;                // NTOT*CC bf16
    unsigned short* W1p  = fcf + (size_t)NTOT * CC;                // CC*K1 bf16 (panels)
    unsigned short* W2p  = W1p + (size_t)CC * K1;                  // CC*K1 bf16 (panels)
    unsigned short* zp   = W2p + (size_t)CC * K1;                  // 1024 zeros

    prep_kernel<<<(CC * K1 + 255) / 256, 256, 0, stream>>>(conv_w, adapt_w, W1p, W2p, zp);
    transpose_kernel<<<dim3(HWP / 64, 4, BB), 256, 0, stream>>>(feature, fcf);
    gemm1_kernel<<<dim3(NTOT / 64 * 2), 512, 0, stream>>>(W1p, fcf, conv_b, zp, tcf);
    heads1_kernel<<<dim3(NTOT / 4), 256, 0, stream>>>(
        tcf, loc_w, loc_b, shape_w, shape_b, out, s0s1);
    gemm2_fused_kernel<<<dim3(NTOT / 32), 256, 0, stream>>>(
        W2p, tcf, s0s1, offset_w, cls_w, cls_b, bbox_w, bbox_b, out);
}